// Round 1
// baseline (111.433 us; speedup 1.0000x reference)
//
#include <hip/hip_runtime.h>

// Problem constants (B=4, N=M=8192, D=3)
#define NPTS   8192
#define BATCH  4
#define BLOCK  256
#define S      8                 // queries per thread (held in registers)
#define QC     (BLOCK * S)       // 2048 queries per block
#define NCHUNK (NPTS / QC)       // 4
#define MC     512               // DB points per block (LDS-staged chunk)
#define MCHUNK (NPTS / MC)       // 16

typedef float v2f __attribute__((ext_vector_type(2)));

__device__ __forceinline__ v2f fma2(v2f a, v2f b, v2f c) {
#if __has_builtin(__builtin_elementwise_fma)
    return __builtin_elementwise_fma(a, b, c);
#else
    return a * b + c;   // ffp-contract=fast folds to fma
#endif
}

// Sign-aware float atomic min (works for mixed-sign values; cell init must be
// a large positive float — we memset 0x7F -> 3.39e38f).
__device__ __forceinline__ void atomic_min_float(float* addr, float val) {
    if (val >= 0.0f) {
        atomicMin((int*)addr, __float_as_int(val));
    } else {
        atomicMax((unsigned int*)addr, __float_as_uint(val));
    }
}

// grid = BATCH * 2 * NCHUNK * MCHUNK = 512 blocks of 256 threads.
// block bid bits: [3:0]=mc, [5:4]=nc, [6]=dir, [8:7]=b
__global__ __launch_bounds__(BLOCK, 2) void chamfer_main(
    const float* __restrict__ src,
    const float* __restrict__ tgt,
    float* __restrict__ minarr)
{
    __shared__ float4 Xs4[MC / 4], Ys4[MC / 4], Zs4[MC / 4], Hs4[MC / 4];
    float* Xs = (float*)Xs4;
    float* Ys = (float*)Ys4;
    float* Zs = (float*)Zs4;
    float* Hs = (float*)Hs4;

    const int bid = blockIdx.x;
    const int mc  = bid & (MCHUNK - 1);
    const int nc  = (bid >> 4) & (NCHUNK - 1);
    const int dir = (bid >> 6) & 1;
    const int b   = bid >> 7;
    const int tid = threadIdx.x;

    const float* Q = dir ? tgt : src;   // dir 0: fwd (src->tgt); dir 1: bwd
    const float* T = dir ? src : tgt;

    // ---- Stage DB chunk into LDS (SoA) with |t|^2 precomputed ----
    const int m0 = mc * MC;
    #pragma unroll
    for (int k = 0; k < MC / BLOCK; ++k) {
        int j = tid + k * BLOCK;
        const float* p = T + ((size_t)b * NPTS + m0 + j) * 3;
        float x = p[0], y = p[1], z = p[2];
        Xs[j] = x; Ys[j] = y; Zs[j] = z;
        Hs[j] = x * x + y * y + z * z;
    }

    // ---- Load S query points; pre-scale by -2, duplicate into pairs ----
    const int n0 = nc * QC;
    v2f   q2x[S], q2y[S], q2z[S];
    float hq[S], mn[S];
    #pragma unroll
    for (int s = 0; s < S; ++s) {
        int n = n0 + tid + s * BLOCK;
        const float* p = Q + ((size_t)b * NPTS + n) * 3;
        float x = p[0], y = p[1], z = p[2];
        v2f ax = {-2.0f * x, -2.0f * x}; q2x[s] = ax;
        v2f ay = {-2.0f * y, -2.0f * y}; q2y[s] = ay;
        v2f az = {-2.0f * z, -2.0f * z}; q2z[s] = az;
        hq[s] = x * x + y * y + z * z;
        mn[s] = 3.0e38f;
    }
    __syncthreads();

    // ---- Inner loop: 4 DB points per iteration (broadcast LDS reads) ----
    #pragma unroll 2
    for (int jq = 0; jq < MC / 4; ++jq) {
        float4 x4 = Xs4[jq], y4 = Ys4[jq], z4 = Zs4[jq], h4 = Hs4[jq];
        v2f xlo = {x4.x, x4.y}, xhi = {x4.z, x4.w};
        v2f ylo = {y4.x, y4.y}, yhi = {y4.z, y4.w};
        v2f zlo = {z4.x, z4.y}, zhi = {z4.z, z4.w};
        v2f hlo = {h4.x, h4.y}, hhi = {h4.z, h4.w};
        #pragma unroll
        for (int s = 0; s < S; ++s) {
            // val = |t|^2 - 2 q.t   (|q|^2 added after the min)
            v2f v01 = fma2(q2x[s], xlo, fma2(q2y[s], ylo, fma2(q2z[s], zlo, hlo)));
            v2f v23 = fma2(q2x[s], xhi, fma2(q2y[s], yhi, fma2(q2z[s], zhi, hhi)));
            mn[s] = fminf(fminf(mn[s], v01.x), v01.y);   // -> v_min3_f32
            mn[s] = fminf(fminf(mn[s], v23.x), v23.y);
        }
    }

    // ---- Combine partial mins across m-chunks via float atomic-min ----
    float* base = minarr + ((size_t)(b * 2 + dir)) * NPTS + n0 + tid;
    #pragma unroll
    for (int s = 0; s < S; ++s) {
        atomic_min_float(base + s * BLOCK, mn[s] + hq[s]);
    }
}

// Single-block final reduction: sum 65536 mins, scale by 1/(B*G).
__global__ __launch_bounds__(1024) void chamfer_reduce(
    const float* __restrict__ minarr, float* __restrict__ out)
{
    __shared__ float sdata[16];
    const int tid = threadIdx.x;
    float acc = 0.0f;
    for (int i = tid; i < BATCH * 2 * NPTS; i += 1024) acc += minarr[i];
    #pragma unroll
    for (int off = 32; off > 0; off >>= 1) acc += __shfl_down(acc, off);
    if ((tid & 63) == 0) sdata[tid >> 6] = acc;
    __syncthreads();
    if (tid == 0) {
        float t = 0.0f;
        #pragma unroll
        for (int w = 0; w < 16; ++w) t += sdata[w];
        out[0] = t * (1.0f / (float)(BATCH * NPTS));
    }
}

extern "C" void kernel_launch(void* const* d_in, const int* in_sizes, int n_in,
                              void* d_out, int out_size, void* d_ws, size_t ws_size,
                              hipStream_t stream) {
    const float* src = (const float*)d_in[0];   // (B, N, 3) fp32
    const float* tgt = (const float*)d_in[1];   // (B, M, 3) fp32
    float* minarr = (float*)d_ws;               // [B][2][NPTS] partial mins
    float* out = (float*)d_out;                 // scalar fp32

    // Init min array to large positive float (0x7F7F7F7F = 3.39e38f).
    hipMemsetAsync(minarr, 0x7F, (size_t)BATCH * 2 * NPTS * sizeof(float), stream);

    chamfer_main<<<BATCH * 2 * NCHUNK * MCHUNK, BLOCK, 0, stream>>>(src, tgt, minarr);
    chamfer_reduce<<<1, 1024, 0, stream>>>(minarr, out);
}

// Round 2
// 105.314 us; speedup vs baseline: 1.0581x; 1.0581x over previous
//
#include <hip/hip_runtime.h>

// Problem constants (B=4, N=M=8192, D=3)
#define NPTS   8192
#define BATCH  4
#define BLOCK  256
#define S      8                  // queries per thread (registers)
#define QC     (BLOCK * S)        // 2048 queries per block
#define NCHUNK (NPTS / QC)        // 4
#define MC     128                // DB points per block (LDS chunk)
#define MCHUNK (NPTS / MC)        // 64
#define NQTOT  (BATCH * 2 * NPTS) // 65536 (queries, both directions)
// grid = BATCH * 2 * NCHUNK * MCHUNK = 2048 blocks -> 8 blocks/CU demanded

// grid decode bits: [5:0]=mc, [7:6]=nc, [8]=dir, [10:9]=b
__global__ __launch_bounds__(BLOCK, 2) void chamfer_main(
    const float* __restrict__ src,
    const float* __restrict__ tgt,
    float* __restrict__ minarr)   // [MCHUNK][NQTOT] partial mins
{
    __shared__ float4 Xs4[MC / 4], Ys4[MC / 4], Zs4[MC / 4], Hs4[MC / 4];
    float* Xs = (float*)Xs4;
    float* Ys = (float*)Ys4;
    float* Zs = (float*)Zs4;
    float* Hs = (float*)Hs4;

    const int bid = blockIdx.x;
    const int mc  = bid & (MCHUNK - 1);
    const int nc  = (bid >> 6) & (NCHUNK - 1);
    const int dir = (bid >> 8) & 1;
    const int b   = bid >> 9;
    const int tid = threadIdx.x;

    const float* Q = dir ? tgt : src;   // dir 0: fwd (src->tgt); dir 1: bwd
    const float* T = dir ? src : tgt;

    // ---- Stage DB chunk into LDS (SoA) with |t|^2 precomputed ----
    const int m0 = mc * MC;
    if (tid < MC) {
        const float* p = T + ((size_t)b * NPTS + m0 + tid) * 3;
        float x = p[0], y = p[1], z = p[2];
        Xs[tid] = x; Ys[tid] = y; Zs[tid] = z;
        Hs[tid] = x * x + y * y + z * z;
    }

    // ---- Load S query points; pre-scale by -2 ----
    const int n0 = nc * QC;
    float qx[S], qy[S], qz[S], mn[S];
    #pragma unroll
    for (int s = 0; s < S; ++s) {
        int n = n0 + tid + s * BLOCK;
        const float* p = Q + ((size_t)b * NPTS + n) * 3;
        qx[s] = -2.0f * p[0];
        qy[s] = -2.0f * p[1];
        qz[s] = -2.0f * p[2];
        mn[s] = 3.0e38f;
    }
    __syncthreads();

    // ---- Inner loop: 4 DB points / iter, broadcast LDS reads ----
    #pragma unroll 2
    for (int jq = 0; jq < MC / 4; ++jq) {
        float4 x4 = Xs4[jq], y4 = Ys4[jq], z4 = Zs4[jq], h4 = Hs4[jq];
        #pragma unroll
        for (int s = 0; s < S; ++s) {
            // val = |t|^2 - 2 q.t   (|q|^2 added after the min)
            float d0 = fmaf(qx[s], x4.x, fmaf(qy[s], y4.x, fmaf(qz[s], z4.x, h4.x)));
            float d1 = fmaf(qx[s], x4.y, fmaf(qy[s], y4.y, fmaf(qz[s], z4.y, h4.y)));
            float d2 = fmaf(qx[s], x4.z, fmaf(qy[s], y4.z, fmaf(qz[s], z4.z, h4.z)));
            float d3 = fmaf(qx[s], x4.w, fmaf(qy[s], y4.w, fmaf(qz[s], z4.w, h4.w)));
            mn[s] = fminf(fminf(mn[s], d0), d1);   // v_min3_f32
            mn[s] = fminf(fminf(mn[s], d2), d3);   // v_min3_f32
        }
    }

    // ---- Store partial mins (every cell written exactly once; no memset) ----
    float* base = minarr + (size_t)mc * NQTOT + ((size_t)(b * 2 + dir)) * NPTS + n0 + tid;
    #pragma unroll
    for (int s = 0; s < S; ++s) {
        // |q|^2 = 0.25*(qx^2+qy^2+qz^2) since q* are pre-scaled by -2
        float hq = 0.25f * fmaf(qx[s], qx[s], fmaf(qy[s], qy[s], qz[s] * qz[s]));
        base[s * BLOCK] = mn[s] + hq;
    }
}

// Parallel reduction: 256 blocks x 256 threads, 1 query each.
// min over MCHUNK partials, then sum-reduce, one atomicAdd per block.
__global__ __launch_bounds__(256) void chamfer_reduce(
    const float* __restrict__ minarr, float* __restrict__ out)
{
    const int q = blockIdx.x * 256 + threadIdx.x;
    float m = 3.4e38f;
    #pragma unroll
    for (int mc = 0; mc < MCHUNK; ++mc)
        m = fminf(m, minarr[(size_t)mc * NQTOT + q]);

    float acc = m;
    #pragma unroll
    for (int off = 32; off > 0; off >>= 1) acc += __shfl_down(acc, off);

    __shared__ float sdata[4];
    if ((threadIdx.x & 63) == 0) sdata[threadIdx.x >> 6] = acc;
    __syncthreads();
    if (threadIdx.x == 0) {
        float t = (sdata[0] + sdata[1]) + (sdata[2] + sdata[3]);
        atomicAdd(out, t * (1.0f / (float)(BATCH * NPTS)));
    }
}

extern "C" void kernel_launch(void* const* d_in, const int* in_sizes, int n_in,
                              void* d_out, int out_size, void* d_ws, size_t ws_size,
                              hipStream_t stream) {
    const float* src = (const float*)d_in[0];   // (B, N, 3) fp32
    const float* tgt = (const float*)d_in[1];   // (B, M, 3) fp32
    float* minarr = (float*)d_ws;               // [MCHUNK][NQTOT] = 16 MB
    float* out = (float*)d_out;                 // scalar fp32

    hipMemsetAsync(out, 0, sizeof(float), stream);  // d_out is poisoned 0xAA
    chamfer_main<<<BATCH * 2 * NCHUNK * MCHUNK, BLOCK, 0, stream>>>(src, tgt, minarr);
    chamfer_reduce<<<NQTOT / 256, 256, 0, stream>>>(minarr, out);
}